// Round 5
// baseline (179.419 us; speedup 1.0000x reference)
//
#include <hip/hip_runtime.h>
#include <cstdint>

#define LX 16384
#define NB 16
#define LT 64
#define HALO 8
#define XI (LT + 2*HALO)     // 80 staged positions
#define XPD 36               // x row pitch in dwords (144 B, 16B-aligned; chunk-rotated)

typedef __attribute__((ext_vector_type(2))) _Float16 h2;
typedef __attribute__((ext_vector_type(8))) _Float16 h8;
typedef __attribute__((ext_vector_type(4))) unsigned u4;
typedef __attribute__((ext_vector_type(4))) float f4;

static __device__ __forceinline__ h2 u2h(unsigned u) {
    union { unsigned u; h2 h; } v; v.u = u; return v.h;
}
static __device__ __forceinline__ unsigned h2u(h2 h) {
    union { h2 h; unsigned u; } v; v.h = h; return v.u;
}
static __device__ __forceinline__ unsigned pkrtz(float a, float b) {
    auto r = __builtin_amdgcn_cvt_pkrtz(a, b);        // __fp16 ext_vector(2)
    union { decltype(r) h; unsigned u; } v; v.h = r;
    return v.u;
}

// ---------------- kernel 0: prep weights into ws (all f16) ----------------
// ws: A2 f16[64][192] @0 (24576 B)  A2[o*192 + tap*64 + c] = weight[o][c][tap]
//   | beff f32[6] @24576 | dwt2 u32[448] @24608 | pwt2 u32[192] @26400
__global__ void prep_kernel(const float* __restrict__ weight,
                            const float* __restrict__ b_off_pw, const float* __restrict__ w_off_pw,
                            const float* __restrict__ b_off_dw,
                            const float* __restrict__ b_msk_pw, const float* __restrict__ w_msk_pw,
                            const float* __restrict__ b_msk_dw,
                            const float* __restrict__ w_off_dw, const float* __restrict__ w_msk_dw,
                            short* __restrict__ A2, float* __restrict__ beff,
                            unsigned* __restrict__ dwt2, unsigned* __restrict__ pwt2) {
    int bid = blockIdx.x;
    int t = threadIdx.x;
    if (bid < 48) {
        int idx = bid * 256 + t;                  // 0..12287 : A2[o][tap*64+c]
        int o = idx / 192;
        int rem = idx - o * 192;
        int tap = rem >> 6, c = rem & 63;
        union { _Float16 h; short s; } v;
        v.h = (_Float16)weight[o * 192 + c * 3 + tap];
        A2[idx] = v.s;
    } else {
        for (int idx = t; idx < 448; idx += 256) {
            int br = idx / 224, r2 = idx - br * 224;
            int j = r2 >> 5, cp = r2 & 31;
            const float* src = br ? w_msk_dw : w_off_dw;
            h2 h; h[0] = (_Float16)src[(2 * cp) * 7 + j]; h[1] = (_Float16)src[(2 * cp + 1) * 7 + j];
            dwt2[idx] = h2u(h);
        }
        if (t < 192) {
            int br = t / 96, r2 = t - br * 96;
            int m = r2 >> 5, cp = r2 & 31;
            const float* src = br ? w_msk_pw : w_off_pw;
            h2 h; h[0] = (_Float16)src[m * 64 + 2 * cp]; h[1] = (_Float16)src[m * 64 + 2 * cp + 1];
            pwt2[t] = h2u(h);
        }
        if (t < 6) {
            int br = t / 3, m = t % 3;
            const float* pw = br ? w_msk_pw : w_off_pw;
            const float* bd = br ? b_msk_dw : b_off_dw;
            const float* bp = br ? b_msk_pw : b_off_pw;
            float s = bp[m];
            for (int c = 0; c < 64; ++c) s += pw[m * 64 + c] * bd[c];
            beff[t] = s;
        }
    }
}

// ---------------- main fused kernel ----------------
__launch_bounds__(256, 5)
__global__ void deform_main(const float* __restrict__ x,
                            const float* __restrict__ bias,
                            const short* __restrict__ A2,
                            const float* __restrict__ beff,
                            const unsigned* __restrict__ dwt2_g,
                            const unsigned* __restrict__ pwt2_g,
                            float* __restrict__ out) {
    // x tile f16 [i][c], c-pairs as dwords; 8-dword chunks rotated by row: phys = (chunk + i) & 3
    __shared__ __align__(16) unsigned xdw[XI * XPD];        // 11520 B
    __shared__ __align__(16) unsigned dwt2[448];            // 1792 B [br][j][cpair]
    __shared__ __align__(16) unsigned pwt2[192];            // 768 B  [br][m][cpair]
    __shared__ unsigned kl_wp[3][64];                       // 768 B  half2(w0,w1)
    __shared__ int      kl_li[3][64];                       // 768 B
    __shared__ float bias_l[64];                            // 256 B
    __shared__ float beff_l[8];                             // 32 B
    // total 15904 B -> LDS allows 8+ blocks/CU; VGPR is the cap

    const int t = threadIdx.x;
    const int l0 = blockIdx.x * LT;
    const int b = blockIdx.y;

    // ---- phase 0: stage x tile ----
    const float* xb = x + (size_t)b * (64 * LX);
    #pragma unroll
    for (int s = 0; s < 3; ++s) {
        int p = t + 256 * s;
        if (p < 640) {
            int cp = p & 31, up = p >> 5;
            int g4 = l0 - HALO + up * 4;
            f4 v0 = {0.f, 0.f, 0.f, 0.f}, v1 = {0.f, 0.f, 0.f, 0.f};
            if ((unsigned)g4 < (unsigned)LX) {
                v0 = *(const f4*)(xb + (size_t)(2 * cp) * LX + g4);
                v1 = *(const f4*)(xb + (size_t)(2 * cp + 1) * LX + g4);
            }
            #pragma unroll
            for (int d = 0; d < 4; ++d) {
                int i = up * 4 + d;
                int pc = ((cp >> 3) + i) & 3;
                xdw[i * XPD + pc * 8 + (cp & 7)] = pkrtz(v0[d], v1[d]);
            }
        }
    }
    for (int idx = t; idx < 448; idx += 256) dwt2[idx] = dwt2_g[idx];
    if (t < 192) pwt2[t] = pwt2_g[t];
    if (t < 64) bias_l[t] = bias[t];
    if (t < 6)  beff_l[t] = beff[t];
    __syncthreads();

    // ---- phase 2: offset/mask conv (pk_fma_f16 + fdot2) + butterfly + coefs ----
    {
        const int l = t >> 2, cc = t & 3;
        h2 so2[8], sm2[8];
        #pragma unroll
        for (int m = 0; m < 8; ++m) { so2[m] = (h2)(_Float16)0; sm2[m] = (h2)(_Float16)0; }
        #pragma unroll
        for (int j = 0; j < 7; ++j) {
            int i = l + 5 + j;                         // global pos (l0+l)-3+j
            const unsigned* xr = &xdw[i * XPD + (((cc + i) & 3) << 3)];
            u4 xa = *(const u4*)xr;
            u4 xb2 = *(const u4*)(xr + 4);
            const unsigned* wo = &dwt2[j * 32 + cc * 8];
            const unsigned* wm = &dwt2[224 + j * 32 + cc * 8];
            u4 woa = *(const u4*)wo, wob = *(const u4*)(wo + 4);
            u4 wma = *(const u4*)wm, wmb = *(const u4*)(wm + 4);
            #pragma unroll
            for (int m = 0; m < 4; ++m) {
                so2[m]     += u2h(xa[m])  * u2h(woa[m]);
                so2[m + 4] += u2h(xb2[m]) * u2h(wob[m]);
                sm2[m]     += u2h(xa[m])  * u2h(wma[m]);
                sm2[m + 4] += u2h(xb2[m]) * u2h(wmb[m]);
            }
        }
        float po[3] = {0.f, 0.f, 0.f}, pm[3] = {0.f, 0.f, 0.f};
        #pragma unroll
        for (int m3 = 0; m3 < 3; ++m3) {
            const unsigned* p0 = &pwt2[m3 * 32 + cc * 8];
            const unsigned* p1 = &pwt2[96 + m3 * 32 + cc * 8];
            u4 a0 = *(const u4*)p0, a1 = *(const u4*)(p0 + 4);
            u4 b0 = *(const u4*)p1, b1 = *(const u4*)(p1 + 4);
            #pragma unroll
            for (int m = 0; m < 4; ++m) {
                po[m3] = __builtin_amdgcn_fdot2(so2[m],     u2h(a0[m]), po[m3], false);
                po[m3] = __builtin_amdgcn_fdot2(so2[m + 4], u2h(a1[m]), po[m3], false);
                pm[m3] = __builtin_amdgcn_fdot2(sm2[m],     u2h(b0[m]), pm[m3], false);
                pm[m3] = __builtin_amdgcn_fdot2(sm2[m + 4], u2h(b1[m]), pm[m3], false);
            }
        }
        #pragma unroll
        for (int d = 1; d <= 2; d <<= 1) {
            #pragma unroll
            for (int m3 = 0; m3 < 3; ++m3) {
                po[m3] += __shfl_xor(po[m3], d);
                pm[m3] += __shfl_xor(pm[m3], d);
            }
        }
        if (cc < 3) {
            int k = cc;
            float off = (k == 0 ? po[0] : k == 1 ? po[1] : po[2]) + beff_l[k];
            float z   = (k == 0 ? pm[0] : k == 1 ? pm[1] : pm[2]) + beff_l[3 + k];
            float msk = 1.0f / (1.0f + __expf(-z));
            float p = (float)(l0 + l - 1 + k) + off;   // ref op order
            float fl = floorf(p);
            int i0 = (int)fl, i1 = i0 + 1;
            float fr = p - fl;
            int li0 = i0 - l0 + HALO, li1 = li0 + 1;
            float w0 = (((unsigned)i0 < (unsigned)LX) && ((unsigned)li0 < (unsigned)XI)) ? (1.0f - fr) * msk : 0.0f;
            float w1 = (((unsigned)i1 < (unsigned)LX) && ((unsigned)li1 < (unsigned)XI)) ? fr * msk : 0.0f;
            li0 = min(max(li0, 0), XI - 2);            // rows li0, li0+1 both staged
            kl_wp[k][l] = pkrtz(w0, w1);
            kl_li[k][l] = li0;
        }
    }
    __syncthreads();

    // ---- phase 3: out[o][l] = W2[o][(tap,c)] @ xs[(tap,c)][l],  M=64 K=192 N=64 ----
    // B-frags built in registers: xs[c][l] = w0*x[c][i0] + w1*x[c][i1] via v_pk_fma_f16.
    {
        const int lane = t & 63;
        const int wv = t >> 6;            // n-tile: cols l = wv*16 + r
        const int r = lane & 15, q = lane >> 4;
        const int lcol = wv * 16 + r;

        h8 bfr[6];
        #pragma unroll
        for (int kk = 0; kk < 6; ++kk) {
            const int tap = kk >> 1;
            unsigned wp = kl_wp[tap][lcol];
            unsigned w00 = __builtin_amdgcn_perm(wp, wp, 0x01000100u);  // (w0,w0)
            unsigned w11 = __builtin_amdgcn_perm(wp, wp, 0x03020302u);  // (w1,w1)
            int li0 = kl_li[tap][lcol];
            int cp0 = (((kk & 1) << 5) + (q << 3)) >> 1;   // dword idx: {0,4,8,...,28}
            int chunkL = cp0 >> 3;
            int o0 = li0 * XPD + ((((chunkL + li0) & 3) << 3) | (cp0 & 7));
            int o1 = (li0 + 1) * XPD + ((((chunkL + li0 + 1) & 3) << 3) | (cp0 & 7));
            u4 r0 = *(const u4*)&xdw[o0];
            u4 r1 = *(const u4*)&xdw[o1];
            u4 xs;
            #pragma unroll
            for (int d = 0; d < 4; ++d)
                xs[d] = h2u(u2h(r0[d]) * u2h(w00) + u2h(r1[d]) * u2h(w11));
            union { u4 u; h8 h; } cvt; cvt.u = xs;
            bfr[kk] = cvt.h;
        }

        const h8* Ap = (const h8*)A2;     // row = 24 h8 (192 f16)
        #pragma unroll
        for (int mt = 0; mt < 4; ++mt) {
            f4 acc = {0.f, 0.f, 0.f, 0.f};
            #pragma unroll
            for (int kk = 0; kk < 6; ++kk) {
                h8 af = Ap[(mt * 16 + r) * 24 + kk * 4 + q];
                acc = __builtin_amdgcn_mfma_f32_16x16x32_f16(af, bfr[kk], acc, 0, 0, 0);
            }
            int ob = mt * 16 + 4 * q;     // D row o = mt*16 + 4q + e, col l = lcol
            float* op = out + ((size_t)b * 64 + ob) * LX + l0 + lcol;
            #pragma unroll
            for (int e = 0; e < 4; ++e)
                op[(size_t)e * LX] = acc[e] + bias_l[ob + e];
        }
    }
}

extern "C" void kernel_launch(void* const* d_in, const int* in_sizes, int n_in,
                              void* d_out, int out_size, void* d_ws, size_t ws_size,
                              hipStream_t stream) {
    const float* x        = (const float*)d_in[0];
    const float* w_off_dw = (const float*)d_in[1];
    const float* b_off_dw = (const float*)d_in[2];
    const float* w_off_pw = (const float*)d_in[3];
    const float* b_off_pw = (const float*)d_in[4];
    const float* w_msk_dw = (const float*)d_in[5];
    const float* b_msk_dw = (const float*)d_in[6];
    const float* w_msk_pw = (const float*)d_in[7];
    const float* b_msk_pw = (const float*)d_in[8];
    const float* weight   = (const float*)d_in[9];
    const float* bias     = (const float*)d_in[10];
    float* out = (float*)d_out;

    short*    A2   = (short*)d_ws;                     // 24576 B
    float*    beff = (float*)((char*)d_ws + 24576);    // 24 B
    unsigned* dwt2 = (unsigned*)((char*)d_ws + 24608); // 1792 B
    unsigned* pwt2 = (unsigned*)((char*)d_ws + 26400); // 768 B

    hipLaunchKernelGGL(prep_kernel, dim3(49), dim3(256), 0, stream,
                       weight, b_off_pw, w_off_pw, b_off_dw, b_msk_pw, w_msk_pw, b_msk_dw,
                       w_off_dw, w_msk_dw, A2, beff, dwt2, pwt2);
    hipLaunchKernelGGL(deform_main, dim3(LX / LT, NB), dim3(256), 0, stream,
                       x, bias, A2, beff, dwt2, pwt2, out);
}

// Round 6
// 155.401 us; speedup vs baseline: 1.1546x; 1.1546x over previous
//
#include <hip/hip_runtime.h>
#include <cstdint>

#define LX 16384
#define NB 16
#define LT 64
#define HALO 8
#define XI (LT + 2*HALO)     // 80 staged positions
#define XPD 36               // x row pitch in dwords (144 B, 16B-aligned; chunk-rotated)

typedef __attribute__((ext_vector_type(2))) _Float16 h2;
typedef __attribute__((ext_vector_type(8))) _Float16 h8;
typedef __attribute__((ext_vector_type(4))) unsigned u4;
typedef __attribute__((ext_vector_type(4))) float f4;

static __device__ __forceinline__ h2 u2h(unsigned u) {
    union { unsigned u; h2 h; } v; v.u = u; return v.h;
}
static __device__ __forceinline__ unsigned h2u(h2 h) {
    union { h2 h; unsigned u; } v; v.h = h; return v.u;
}
static __device__ __forceinline__ unsigned pkrtz(float a, float b) {
    auto r = __builtin_amdgcn_cvt_pkrtz(a, b);        // __fp16 ext_vector(2)
    union { decltype(r) h; unsigned u; } v; v.h = r;
    return v.u;
}

// ---------------- kernel 0: prep weights into ws (all f16) ----------------
// ws: A2 f16[64][192] @0 (24576 B)  A2[o*192 + tap*64 + c] = weight[o][c][tap]
//   | beff f32[6] @24576 | dwt2 u32[448] @24608 | pwt2 u32[192] @26400
__global__ void prep_kernel(const float* __restrict__ weight,
                            const float* __restrict__ b_off_pw, const float* __restrict__ w_off_pw,
                            const float* __restrict__ b_off_dw,
                            const float* __restrict__ b_msk_pw, const float* __restrict__ w_msk_pw,
                            const float* __restrict__ b_msk_dw,
                            const float* __restrict__ w_off_dw, const float* __restrict__ w_msk_dw,
                            short* __restrict__ A2, float* __restrict__ beff,
                            unsigned* __restrict__ dwt2, unsigned* __restrict__ pwt2) {
    int bid = blockIdx.x;
    int t = threadIdx.x;
    if (bid < 48) {
        int idx = bid * 256 + t;                  // 0..12287 : A2[o][tap*64+c]
        int o = idx / 192;
        int rem = idx - o * 192;
        int tap = rem >> 6, c = rem & 63;
        union { _Float16 h; short s; } v;
        v.h = (_Float16)weight[o * 192 + c * 3 + tap];
        A2[idx] = v.s;
    } else {
        for (int idx = t; idx < 448; idx += 256) {
            int br = idx / 224, r2 = idx - br * 224;
            int j = r2 >> 5, cp = r2 & 31;
            const float* src = br ? w_msk_dw : w_off_dw;
            h2 h; h[0] = (_Float16)src[(2 * cp) * 7 + j]; h[1] = (_Float16)src[(2 * cp + 1) * 7 + j];
            dwt2[idx] = h2u(h);
        }
        if (t < 192) {
            int br = t / 96, r2 = t - br * 96;
            int m = r2 >> 5, cp = r2 & 31;
            const float* src = br ? w_msk_pw : w_off_pw;
            h2 h; h[0] = (_Float16)src[m * 64 + 2 * cp]; h[1] = (_Float16)src[m * 64 + 2 * cp + 1];
            pwt2[t] = h2u(h);
        }
        if (t < 6) {
            int br = t / 3, m = t % 3;
            const float* pw = br ? w_msk_pw : w_off_pw;
            const float* bd = br ? b_msk_dw : b_off_dw;
            const float* bp = br ? b_msk_pw : b_off_pw;
            float s = bp[m];
            for (int c = 0; c < 64; ++c) s += pw[m * 64 + c] * bd[c];
            beff[t] = s;
        }
    }
}

// ---------------- main fused kernel ----------------
__launch_bounds__(256, 4)
__global__ void deform_main(const float* __restrict__ x,
                            const float* __restrict__ bias,
                            const short* __restrict__ A2,
                            const float* __restrict__ beff,
                            const unsigned* __restrict__ dwt2_g,
                            const unsigned* __restrict__ pwt2_g,
                            float* __restrict__ out) {
    // x tile f16 [i][c], c-pairs as dwords; 8-dword chunks rotated by row: phys = (chunk + i) & 3
    __shared__ __align__(16) unsigned xdw[XI * XPD];        // 11520 B
    // A2 staged in LDS, XOR-swizzled: phys_dw = row*96 + (dw ^ ((row&7)<<2))
    __shared__ __align__(16) unsigned A2l[6144];            // 24576 B
    __shared__ __align__(16) unsigned dwt2[448];            // 1792 B [br][j][cpair]
    __shared__ __align__(16) unsigned pwt2[192];            // 768 B  [br][m][cpair]
    __shared__ unsigned kl_wp[3][64];                       // 768 B  half2(w0,w1)
    __shared__ int      kl_li[3][64];                       // 768 B
    __shared__ float bias_l[64];                            // 256 B
    __shared__ float beff_l[8];                             // 32 B
    // total 40480 B -> 4 blocks/CU

    const int t = threadIdx.x;
    const int l0 = blockIdx.x * LT;
    const int b = blockIdx.y;

    // ---- phase 0: stage x tile + A2 + weights ----
    const float* xb = x + (size_t)b * (64 * LX);
    #pragma unroll
    for (int s = 0; s < 3; ++s) {
        int p = t + 256 * s;
        if (p < 640) {
            int cp = p & 31, up = p >> 5;
            int g4 = l0 - HALO + up * 4;
            f4 v0 = {0.f, 0.f, 0.f, 0.f}, v1 = {0.f, 0.f, 0.f, 0.f};
            if ((unsigned)g4 < (unsigned)LX) {
                v0 = *(const f4*)(xb + (size_t)(2 * cp) * LX + g4);
                v1 = *(const f4*)(xb + (size_t)(2 * cp + 1) * LX + g4);
            }
            #pragma unroll
            for (int d = 0; d < 4; ++d) {
                int i = up * 4 + d;
                int pc = ((cp >> 3) + i) & 3;
                xdw[i * XPD + pc * 8 + (cp & 7)] = pkrtz(v0[d], v1[d]);
            }
        }
    }
    {
        const u4* A2g4 = (const u4*)A2;          // 1536 u4, coalesced 16B/lane
        #pragma unroll
        for (int s = 0; s < 6; ++s) {
            int idx = t + 256 * s;               // 0..1535
            int row = idx / 24;
            int g = idx - row * 24;
            int pdw = row * 96 + ((g * 4) ^ ((row & 7) << 2));
            *(u4*)&A2l[pdw] = A2g4[idx];
        }
    }
    for (int idx = t; idx < 448; idx += 256) dwt2[idx] = dwt2_g[idx];
    if (t < 192) pwt2[t] = pwt2_g[t];
    if (t < 64) bias_l[t] = bias[t];
    if (t < 6)  beff_l[t] = beff[t];
    __syncthreads();

    // ---- phase 2: offset/mask conv (pk_fma_f16 + fdot2) + butterfly + coefs ----
    {
        const int l = t >> 2, cc = t & 3;
        h2 so2[8], sm2[8];
        #pragma unroll
        for (int m = 0; m < 8; ++m) { so2[m] = (h2)(_Float16)0; sm2[m] = (h2)(_Float16)0; }
        #pragma unroll
        for (int j = 0; j < 7; ++j) {
            int i = l + 5 + j;                         // global pos (l0+l)-3+j
            const unsigned* xr = &xdw[i * XPD + (((cc + i) & 3) << 3)];
            u4 xa = *(const u4*)xr;
            u4 xb2 = *(const u4*)(xr + 4);
            const unsigned* wo = &dwt2[j * 32 + cc * 8];
            const unsigned* wm = &dwt2[224 + j * 32 + cc * 8];
            u4 woa = *(const u4*)wo, wob = *(const u4*)(wo + 4);
            u4 wma = *(const u4*)wm, wmb = *(const u4*)(wm + 4);
            #pragma unroll
            for (int m = 0; m < 4; ++m) {
                so2[m]     += u2h(xa[m])  * u2h(woa[m]);
                so2[m + 4] += u2h(xb2[m]) * u2h(wob[m]);
                sm2[m]     += u2h(xa[m])  * u2h(wma[m]);
                sm2[m + 4] += u2h(xb2[m]) * u2h(wmb[m]);
            }
        }
        float po[3] = {0.f, 0.f, 0.f}, pm[3] = {0.f, 0.f, 0.f};
        #pragma unroll
        for (int m3 = 0; m3 < 3; ++m3) {
            const unsigned* p0 = &pwt2[m3 * 32 + cc * 8];
            const unsigned* p1 = &pwt2[96 + m3 * 32 + cc * 8];
            u4 a0 = *(const u4*)p0, a1 = *(const u4*)(p0 + 4);
            u4 b0 = *(const u4*)p1, b1 = *(const u4*)(p1 + 4);
            #pragma unroll
            for (int m = 0; m < 4; ++m) {
                po[m3] = __builtin_amdgcn_fdot2(so2[m],     u2h(a0[m]), po[m3], false);
                po[m3] = __builtin_amdgcn_fdot2(so2[m + 4], u2h(a1[m]), po[m3], false);
                pm[m3] = __builtin_amdgcn_fdot2(sm2[m],     u2h(b0[m]), pm[m3], false);
                pm[m3] = __builtin_amdgcn_fdot2(sm2[m + 4], u2h(b1[m]), pm[m3], false);
            }
        }
        #pragma unroll
        for (int d = 1; d <= 2; d <<= 1) {
            #pragma unroll
            for (int m3 = 0; m3 < 3; ++m3) {
                po[m3] += __shfl_xor(po[m3], d);
                pm[m3] += __shfl_xor(pm[m3], d);
            }
        }
        if (cc < 3) {
            int k = cc;
            float off = (k == 0 ? po[0] : k == 1 ? po[1] : po[2]) + beff_l[k];
            float z   = (k == 0 ? pm[0] : k == 1 ? pm[1] : pm[2]) + beff_l[3 + k];
            float msk = 1.0f / (1.0f + __expf(-z));
            float p = (float)(l0 + l - 1 + k) + off;   // ref op order
            float fl = floorf(p);
            int i0 = (int)fl, i1 = i0 + 1;
            float fr = p - fl;
            int li0 = i0 - l0 + HALO, li1 = li0 + 1;
            float w0 = (((unsigned)i0 < (unsigned)LX) && ((unsigned)li0 < (unsigned)XI)) ? (1.0f - fr) * msk : 0.0f;
            float w1 = (((unsigned)i1 < (unsigned)LX) && ((unsigned)li1 < (unsigned)XI)) ? fr * msk : 0.0f;
            li0 = min(max(li0, 0), XI - 2);            // rows li0, li0+1 both staged
            kl_wp[k][l] = pkrtz(w0, w1);
            kl_li[k][l] = li0;
        }
    }
    __syncthreads();

    // ---- phase 3: out[o][l] = W2[o][(tap,c)] @ xs[(tap,c)][l],  M=64 K=192 N=64 ----
    // B-frags built in registers: xs[c][l] = w0*x[c][i0] + w1*x[c][i1] via v_pk_fma_f16.
    // A-frags from LDS (swizzled), ds_read_b128.
    {
        const int lane = t & 63;
        const int wv = t >> 6;            // n-tile: cols l = wv*16 + r
        const int r = lane & 15, q = lane >> 4;
        const int lcol = wv * 16 + r;

        h8 bfr[6];
        #pragma unroll
        for (int kk = 0; kk < 6; ++kk) {
            const int tap = kk >> 1;
            unsigned wp = kl_wp[tap][lcol];
            unsigned w00 = __builtin_amdgcn_perm(wp, wp, 0x01000100u);  // (w0,w0)
            unsigned w11 = __builtin_amdgcn_perm(wp, wp, 0x03020302u);  // (w1,w1)
            int li0 = kl_li[tap][lcol];
            int cp0 = (((kk & 1) << 5) + (q << 3)) >> 1;   // dword idx: {0,4,...,28}
            int chunkL = cp0 >> 3;
            int o0 = li0 * XPD + ((((chunkL + li0) & 3) << 3) | (cp0 & 7));
            int o1 = (li0 + 1) * XPD + ((((chunkL + li0 + 1) & 3) << 3) | (cp0 & 7));
            u4 r0 = *(const u4*)&xdw[o0];
            u4 r1 = *(const u4*)&xdw[o1];
            u4 xs;
            #pragma unroll
            for (int d = 0; d < 4; ++d)
                xs[d] = h2u(u2h(r0[d]) * u2h(w00) + u2h(r1[d]) * u2h(w11));
            union { u4 u; h8 h; } cvt; cvt.u = xs;
            bfr[kk] = cvt.h;
        }

        #pragma unroll
        for (int mt = 0; mt < 4; ++mt) {
            f4 acc = {0.f, 0.f, 0.f, 0.f};
            const int row = mt * 16 + r;
            const int rowbase = row * 96;
            const int sw = (r & 7) << 2;
            #pragma unroll
            for (int kk = 0; kk < 6; ++kk) {
                union { u4 u; h8 h; } af;
                af.u = *(const u4*)&A2l[rowbase + ((kk * 16 + q * 4) ^ sw)];
                acc = __builtin_amdgcn_mfma_f32_16x16x32_f16(af.h, bfr[kk], acc, 0, 0, 0);
            }
            int ob = mt * 16 + 4 * q;     // D row o = mt*16 + 4q + e, col l = lcol
            float* op = out + ((size_t)b * 64 + ob) * LX + l0 + lcol;
            #pragma unroll
            for (int e = 0; e < 4; ++e)
                op[(size_t)e * LX] = acc[e] + bias_l[ob + e];
        }
    }
}

extern "C" void kernel_launch(void* const* d_in, const int* in_sizes, int n_in,
                              void* d_out, int out_size, void* d_ws, size_t ws_size,
                              hipStream_t stream) {
    const float* x        = (const float*)d_in[0];
    const float* w_off_dw = (const float*)d_in[1];
    const float* b_off_dw = (const float*)d_in[2];
    const float* w_off_pw = (const float*)d_in[3];
    const float* b_off_pw = (const float*)d_in[4];
    const float* w_msk_dw = (const float*)d_in[5];
    const float* b_msk_dw = (const float*)d_in[6];
    const float* w_msk_pw = (const float*)d_in[7];
    const float* b_msk_pw = (const float*)d_in[8];
    const float* weight   = (const float*)d_in[9];
    const float* bias     = (const float*)d_in[10];
    float* out = (float*)d_out;

    short*    A2   = (short*)d_ws;                     // 24576 B
    float*    beff = (float*)((char*)d_ws + 24576);    // 24 B
    unsigned* dwt2 = (unsigned*)((char*)d_ws + 24608); // 1792 B
    unsigned* pwt2 = (unsigned*)((char*)d_ws + 26400); // 768 B

    hipLaunchKernelGGL(prep_kernel, dim3(49), dim3(256), 0, stream,
                       weight, b_off_pw, w_off_pw, b_off_dw, b_msk_pw, w_msk_pw, b_msk_dw,
                       w_off_dw, w_msk_dw, A2, beff, dwt2, pwt2);
    hipLaunchKernelGGL(deform_main, dim3(LX / LT, NB), dim3(256), 0, stream,
                       x, bias, A2, beff, dwt2, pwt2, out);
}